// Round 1
// baseline (241.496 us; speedup 1.0000x reference)
//
#include <hip/hip_runtime.h>

#define TB 512
#define TF 1280
#define TH 2560
#define TK 8
#define TE 9

typedef __attribute__((ext_vector_type(8))) short short8;
typedef __attribute__((ext_vector_type(4))) short short4v;
typedef __attribute__((ext_vector_type(4))) float floatx4;

__device__ __forceinline__ short f2bf(float f) {
  union { float f; unsigned u; } v; v.f = f;
  unsigned r = v.u + 0x7fffu + ((v.u >> 16) & 1u);   // RNE
  return (short)(r >> 16);
}

// Kernel 1: h[e,b,hcol] = relu(x @ W1[e] + b1[e])  -> bf16 in ws
// Tiles: BM=128, BN=128, BK=32. 256 threads = 4 waves (2x2), each wave 64x64 via
// 4x4 fragments of mfma_f32_16x16x32_bf16.
__global__ __launch_bounds__(256) void gemm1_relu(
    const float* __restrict__ x, const float* __restrict__ W1,
    const float* __restrict__ b1, short* __restrict__ h) {
  // Padded leading dim 40 (=32+8): rows are 80B (16B-aligned), bank aliasing <=2-way.
  __shared__ __align__(16) short As[128 * 40];  // As[m][k]  k-contiguous
  __shared__ __align__(16) short Bs[128 * 40];  // Bs[n][k]  k-contiguous (transposed)
  const int t = threadIdx.x;
  const int tileN = blockIdx.x;       // 0..179  (e = tileN/20, hbase = (tileN%20)*128)
  const int tileM = blockIdx.y;       // 0..3
  const int e = tileN / 20;
  const int hbase = (tileN % 20) * 128;
  const int m0 = tileM * 128;

  const int lane = t & 63, w = t >> 6;
  const int wm = w & 1, wn = w >> 1;
  const int lm = lane & 15, lq = lane >> 4;
  const int lk = lq * 8;

  floatx4 acc[4][4];
#pragma unroll
  for (int i = 0; i < 4; ++i)
#pragma unroll
    for (int j = 0; j < 4; ++j) acc[i][j] = (floatx4){0.f, 0.f, 0.f, 0.f};

  const float* wp = W1 + (long)e * TF * TH + hbase;  // W1[e][k][hbase+..]
  const int cA = (t & 7) * 4;   // A k-offset
  const int mA = t >> 3;        // A row base (0..31)
  const int nB = t & 127;       // B column (within tile)
  const int gB = t >> 7;        // 0/1 -> k half

  for (int kt = 0; kt < TF / 32; ++kt) {
    const int k0 = kt * 32;
    if (kt) __syncthreads();
    // Stage A: x[m0+m][k0+c], fp32 float4 -> 4x bf16
#pragma unroll
    for (int i = 0; i < 4; ++i) {
      const int m = mA + 32 * i;
      floatx4 v = *(const floatx4*)(x + (long)(m0 + m) * TF + k0 + cA);
      short4v s; s.x = f2bf(v.x); s.y = f2bf(v.y); s.z = f2bf(v.z); s.w = f2bf(v.w);
      *(short4v*)&As[m * 40 + cA] = s;
    }
    // Stage B transposed: Bs[n][k] = W1[e][k0+k][hbase+n]; scalar loads coalesced over n
    {
      const float* bp = wp + (long)k0 * TH + nB;
#pragma unroll
      for (int q = 0; q < 4; ++q) {
        const int k4 = gB * 16 + q * 4;
        float f0 = bp[(long)(k4 + 0) * TH];
        float f1 = bp[(long)(k4 + 1) * TH];
        float f2 = bp[(long)(k4 + 2) * TH];
        float f3 = bp[(long)(k4 + 3) * TH];
        short4v s; s.x = f2bf(f0); s.y = f2bf(f1); s.z = f2bf(f2); s.w = f2bf(f3);
        *(short4v*)&Bs[nB * 40 + k4] = s;
      }
    }
    __syncthreads();
    short8 af[4], bfr[4];
#pragma unroll
    for (int mg = 0; mg < 4; ++mg)
      af[mg] = *(const short8*)&As[(wm * 64 + mg * 16 + lm) * 40 + lk];
#pragma unroll
    for (int ng = 0; ng < 4; ++ng)
      bfr[ng] = *(const short8*)&Bs[(wn * 64 + ng * 16 + lm) * 40 + lk];
#pragma unroll
    for (int mg = 0; mg < 4; ++mg)
#pragma unroll
      for (int ng = 0; ng < 4; ++ng)
        acc[mg][ng] = __builtin_amdgcn_mfma_f32_16x16x32_bf16(af[mg], bfr[ng], acc[mg][ng], 0, 0, 0);
  }

  // Epilogue: C/D layout col=lane&15, row=(lane>>4)*4+reg  (m89/m91-verified)
#pragma unroll
  for (int mg = 0; mg < 4; ++mg) {
    const int row = m0 + wm * 64 + mg * 16 + lq * 4;
#pragma unroll
    for (int ng = 0; ng < 4; ++ng) {
      const int col = hbase + wn * 64 + ng * 16 + lm;
      const float bias = b1[e * TH + col];
      floatx4 c = acc[mg][ng];
#pragma unroll
      for (int r = 0; r < 4; ++r) {
        float v = c[r] + bias;
        v = v > 0.f ? v : 0.f;
        h[((long)e * TB + row + r) * TH + col] = f2bf(v);
      }
    }
  }
}

// Kernel 2: logits[e,b,k] = h[e,b,:] @ W2[e][:,k] + b2[e,k]; softmax -> probs.
// Block = (expert, 64-row tile); 4 waves x 16 rows; A-frags straight from global h.
__global__ __launch_bounds__(256) void gemm2_softmax(
    const short* __restrict__ h, const float* __restrict__ W2,
    const float* __restrict__ b2, float* __restrict__ logits_out,
    float* __restrict__ probs) {
  __shared__ __align__(16) short W2t[8 * 2568];  // W2t[n][k] bf16, padded rows
  const int t = threadIdx.x;
  const int e = blockIdx.x >> 3;
  const int bt = blockIdx.x & 7;

  {  // stage W2[e] transposed to bf16
    const int n = t & 7;
    const int kstart = (t >> 3) * 80;
    const float* wp = W2 + (long)e * TH * TK + n;
    for (int j = 0; j < 80; ++j) {
      const int k = kstart + j;
      W2t[n * 2568 + k] = f2bf(wp[(long)k * TK]);
    }
  }
  __syncthreads();

  const int lane = t & 63, w = t >> 6;
  const int lm = lane & 15, lq = lane >> 4, lk = lq * 8;
  const int rb = bt * 64 + w * 16;
  const short* hp = h + ((long)e * TB + rb + lm) * TH + lk;

  floatx4 acc = (floatx4){0.f, 0.f, 0.f, 0.f};
  const short8 zero8 = {0, 0, 0, 0, 0, 0, 0, 0};
  for (int kt = 0; kt < TH / 32; ++kt) {
    short8 a = *(const short8*)(hp + kt * 32);
    short8 b = (lm < 8) ? *(const short8*)&W2t[lm * 2568 + kt * 32 + lk] : zero8;
    acc = __builtin_amdgcn_mfma_f32_16x16x32_bf16(a, b, acc, 0, 0, 0);
  }

  // acc[r] -> logits[rb + lq*4 + r][lm] (valid for lm<8). Softmax over lane bits 0..2.
  const float bias = b2[e * TK + (lm & 7)];
  float lg[4], pr[4];
#pragma unroll
  for (int r = 0; r < 4; ++r) {
    float v = acc[r] + bias;
    float mx = v;
    mx = fmaxf(mx, __shfl_xor(mx, 1, 64));
    mx = fmaxf(mx, __shfl_xor(mx, 2, 64));
    mx = fmaxf(mx, __shfl_xor(mx, 4, 64));
    float ex = __expf(v - mx);
    float sm = ex;
    sm += __shfl_xor(sm, 1, 64);
    sm += __shfl_xor(sm, 2, 64);
    sm += __shfl_xor(sm, 4, 64);
    lg[r] = v;
    pr[r] = ex / sm;
  }
  if (lm < 8) {
#pragma unroll
    for (int r = 0; r < 4; ++r) {
      const long idx = ((long)e * TB + rb + lq * 4 + r) * TK + lm;
      logits_out[idx] = lg[r];
      probs[idx] = pr[r];
    }
  }
}

// Kernel 3: leaf_probs[b, 0..72]
__global__ __launch_bounds__(256) void leafk(const float* __restrict__ probs,
                                             float* __restrict__ out) {
  const int idx = blockIdx.x * 256 + threadIdx.x;
  if (idx >= TB * 73) return;
  const int b = idx / 73, c = idx % 73;
  float v;
  if (c == 0) {
    v = 1.0f;
  } else if (c < 9) {
    v = probs[(long)b * TK + (c - 1)];
  } else {
    const int i = (c - 9) >> 3, j = (c - 9) & 7;
    v = probs[(long)b * TK + i] * probs[((long)(1 + i) * TB + b) * TK + j];
  }
  out[idx] = v;
}

extern "C" void kernel_launch(void* const* d_in, const int* in_sizes, int n_in,
                              void* d_out, int out_size, void* d_ws, size_t ws_size,
                              hipStream_t stream) {
  const float* x  = (const float*)d_in[0];
  const float* W1 = (const float*)d_in[1];
  const float* b1 = (const float*)d_in[2];
  const float* W2 = (const float*)d_in[3];
  const float* b2 = (const float*)d_in[4];
  float* out = (float*)d_out;

  short* h = (short*)d_ws;                                        // [9][512][2560] bf16
  float* probs = (float*)((char*)d_ws + (size_t)TE * TB * TH * 2);  // [9][512][8] f32
  float* logits_out = out + TB * 73;                              // second tuple element

  gemm1_relu<<<dim3(180, 4), 256, 0, stream>>>(x, W1, b1, h);
  gemm2_softmax<<<TE * 8, 256, 0, stream>>>(h, W2, b2, logits_out, probs);
  leafk<<<(TB * 73 + 255) / 256, 256, 0, stream>>>(probs, out);
}